// Round 1
// baseline (493.663 us; speedup 1.0000x reference)
//
#include <hip/hip_runtime.h>

#define N_NODES 100000
#define N_EDGES 1600000
#define D 64

// support = X @ W. One block = 4 rows x 64 cols, W staged in LDS.
__global__ __launch_bounds__(256) void gcn_gemm(const float* __restrict__ x,
                                                const float* __restrict__ w,
                                                float* __restrict__ support) {
    __shared__ float wl[D * D];   // 16 KB
    __shared__ float xl[4 * D];   // 1 KB
    int tid = threadIdx.x;
    for (int i = tid; i < D * D; i += 256) wl[i] = w[i];

    int row0 = blockIdx.x * 4;
    int r = tid >> 6;        // 0..3
    int col = tid & 63;
    int row = row0 + r;
    // stage the 4 x-rows (256 floats, one per thread)
    int grow = row0 + (tid >> 6);
    if (grow < N_NODES) xl[tid] = x[grow * D + col];
    __syncthreads();

    if (row >= N_NODES) return;
    float acc = 0.f;
    #pragma unroll
    for (int k = 0; k < D; ++k) {
        acc += xl[r * D + k] * wl[k * D + col];  // xl read is wave-uniform (broadcast)
    }
    support[row * D + col] = acc;
}

// out[n][d] = bias[d]
__global__ __launch_bounds__(256) void gcn_init(float* __restrict__ out,
                                                const float* __restrict__ bias) {
    int idx = blockIdx.x * 256 + threadIdx.x;
    if (idx < N_NODES * D) out[idx] = bias[idx & 63];
}

// one wave per edge; lane = feature dim
__global__ __launch_bounds__(256) void gcn_scatter(const float* __restrict__ support,
                                                   const float* __restrict__ adj,
                                                   const int* __restrict__ src,
                                                   const int* __restrict__ dst,
                                                   float* __restrict__ out) {
    int tid = threadIdx.x;
    int e = blockIdx.x * 4 + (tid >> 6);
    if (e >= N_EDGES) return;
    int lane = tid & 63;
    int s = src[e];
    int d = dst[e];
    float a = adj[e];
    float v = a * support[s * D + lane];
    atomicAdd(&out[d * D + lane], v);
}

extern "C" void kernel_launch(void* const* d_in, const int* in_sizes, int n_in,
                              void* d_out, int out_size, void* d_ws, size_t ws_size,
                              hipStream_t stream) {
    const float* x      = (const float*)d_in[0];
    const float* weight = (const float*)d_in[1];
    const float* bias   = (const float*)d_in[2];
    const float* adj    = (const float*)d_in[3];
    const int*   src    = (const int*)d_in[4];
    const int*   dst    = (const int*)d_in[5];
    float* out = (float*)d_out;
    float* support = (float*)d_ws;   // 100000*64*4 = 25.6 MB

    hipLaunchKernelGGL(gcn_gemm, dim3((N_NODES + 3) / 4), dim3(256), 0, stream,
                       x, weight, support);
    hipLaunchKernelGGL(gcn_init, dim3((N_NODES * D) / 256), dim3(256), 0, stream,
                       out, bias);
    hipLaunchKernelGGL(gcn_scatter, dim3(N_EDGES / 4), dim3(256), 0, stream,
                       support, adj, src, dst, out);
}

// Round 2
// 481.545 us; speedup vs baseline: 1.0252x; 1.0252x over previous
//
#include <hip/hip_runtime.h>

#define N_NODES 100000
#define N_EDGES 1600000
#define D 64

// ---------------- GEMM: support = X @ W ----------------
// 128 rows x 64 cols per block, 256 threads, 8x4 register blocking.
// xs stride 68 floats: lanes read rows tr+16j -> start banks {0,4,8,12}, conflict-free b128.
#define GR 128
__global__ __launch_bounds__(256) void gcn_gemm(const float* __restrict__ x,
                                                const float* __restrict__ w,
                                                float* __restrict__ support) {
    __shared__ float xs[GR * 68];
    __shared__ float wsh[64 * 68];
    int tid = threadIdx.x;
    int rbase = blockIdx.x * GR;

    const float4* w4 = (const float4*)w;
    for (int i = tid; i < 64 * 16; i += 256) {
        int k = i >> 4, c4 = i & 15;
        *(float4*)&wsh[k * 68 + c4 * 4] = w4[k * 16 + c4];
    }
    const float4* x4 = (const float4*)x;
    for (int i = tid; i < GR * 16; i += 256) {
        int r = i >> 4, k4 = i & 15;
        int gr = rbase + r;
        float4 v = make_float4(0.f, 0.f, 0.f, 0.f);
        if (gr < N_NODES) v = x4[gr * 16 + k4];
        *(float4*)&xs[r * 68 + k4 * 4] = v;
    }
    __syncthreads();

    int tc = tid & 15, tr = tid >> 4;
    int c0 = tc * 4;
    float4 acc[8];
    #pragma unroll
    for (int j = 0; j < 8; ++j) acc[j] = make_float4(0.f, 0.f, 0.f, 0.f);

    #pragma unroll
    for (int k0 = 0; k0 < 64; k0 += 4) {
        float4 wv0 = *(const float4*)&wsh[(k0 + 0) * 68 + c0];
        float4 wv1 = *(const float4*)&wsh[(k0 + 1) * 68 + c0];
        float4 wv2 = *(const float4*)&wsh[(k0 + 2) * 68 + c0];
        float4 wv3 = *(const float4*)&wsh[(k0 + 3) * 68 + c0];
        #pragma unroll
        for (int j = 0; j < 8; ++j) {
            float4 xv = *(const float4*)&xs[(tr + 16 * j) * 68 + k0];
            acc[j] += wv0 * xv.x + wv1 * xv.y + wv2 * xv.z + wv3 * xv.w;
        }
    }
    #pragma unroll
    for (int j = 0; j < 8; ++j) {
        int gr = rbase + tr + 16 * j;
        if (gr < N_NODES) *(float4*)&support[gr * D + c0] = acc[j];
    }
}

// ---------------- binning: counting sort by dst ----------------
__global__ __launch_bounds__(256) void gcn_count(const int* __restrict__ dst,
                                                 int* __restrict__ counts) {
    int e = blockIdx.x * 256 + threadIdx.x;
    if (e < N_EDGES) atomicAdd(&counts[dst[e]], 1);
}

#define SCAN_B 1024
__global__ __launch_bounds__(256) void gcn_scan1(const int* __restrict__ counts,
                                                 int* __restrict__ offs,
                                                 int* __restrict__ bsums) {
    __shared__ int sh[256];
    int tid = threadIdx.x;
    int base = blockIdx.x * SCAN_B + tid * 4;
    int v0 = (base + 0 < N_NODES) ? counts[base + 0] : 0;
    int v1 = (base + 1 < N_NODES) ? counts[base + 1] : 0;
    int v2 = (base + 2 < N_NODES) ? counts[base + 2] : 0;
    int v3 = (base + 3 < N_NODES) ? counts[base + 3] : 0;
    int local = v0 + v1 + v2 + v3;
    sh[tid] = local;
    __syncthreads();
    for (int off = 1; off < 256; off <<= 1) {
        int t = 0;
        if (tid >= off) t = sh[tid - off];
        __syncthreads();
        if (tid >= off) sh[tid] += t;
        __syncthreads();
    }
    int excl = sh[tid] - local;
    if (base + 0 < N_NODES) offs[base + 0] = excl;
    if (base + 1 < N_NODES) offs[base + 1] = excl + v0;
    if (base + 2 < N_NODES) offs[base + 2] = excl + v0 + v1;
    if (base + 3 < N_NODES) offs[base + 3] = excl + v0 + v1 + v2;
    if (tid == 255) bsums[blockIdx.x] = sh[255];
}

#define NB1 98  // ceil(100000/1024)
__global__ __launch_bounds__(128) void gcn_scan2(int* __restrict__ bsums) {
    __shared__ int sh[128];
    int tid = threadIdx.x;
    int orig = (tid < NB1) ? bsums[tid] : 0;
    sh[tid] = orig;
    __syncthreads();
    for (int off = 1; off < 128; off <<= 1) {
        int t = 0;
        if (tid >= off) t = sh[tid - off];
        __syncthreads();
        if (tid >= off) sh[tid] += t;
        __syncthreads();
    }
    if (tid < NB1) bsums[tid] = sh[tid] - orig;  // exclusive
}

__global__ __launch_bounds__(256) void gcn_scan3(int* __restrict__ offs,
                                                 const int* __restrict__ bsums,
                                                 int* __restrict__ cursor) {
    int i = blockIdx.x * 256 + threadIdx.x;
    if (i < N_NODES) {
        int o = offs[i] + bsums[i >> 10];
        offs[i] = o;
        cursor[i] = o;
    }
}

__global__ __launch_bounds__(256) void gcn_fill(const int* __restrict__ src,
                                                const int* __restrict__ dst,
                                                const float* __restrict__ adj,
                                                int* __restrict__ cursor,
                                                int2* __restrict__ edges) {
    int e = blockIdx.x * 256 + threadIdx.x;
    if (e < N_EDGES) {
        int d = dst[e];
        int pos = atomicAdd(&cursor[d], 1);
        edges[pos] = make_int2(src[e], __float_as_int(adj[e]));
    }
}

// ---------------- gather: one wave per node, atomic-free ----------------
__global__ __launch_bounds__(256) void gcn_gather(const float* __restrict__ support,
                                                  const int2* __restrict__ edges,
                                                  const int* __restrict__ offs,
                                                  const int* __restrict__ counts,
                                                  const float* __restrict__ bias,
                                                  float* __restrict__ out) {
    int tid = threadIdx.x;
    int n = blockIdx.x * 4 + (tid >> 6);
    if (n >= N_NODES) return;
    int lane = tid & 63;
    int start = offs[n];
    int cnt = counts[n];
    float acc = bias[lane];
    int i = 0;
    for (; i + 2 <= cnt; i += 2) {
        int2 e0 = edges[start + i];
        int2 e1 = edges[start + i + 1];
        float v0 = support[(long)e0.x * D + lane];
        float v1 = support[(long)e1.x * D + lane];
        acc += __int_as_float(e0.y) * v0;
        acc += __int_as_float(e1.y) * v1;
    }
    if (i < cnt) {
        int2 e0 = edges[start + i];
        acc += __int_as_float(e0.y) * support[(long)e0.x * D + lane];
    }
    out[(long)n * D + lane] = acc;
}

// ---------------- fallback (round-1 atomic path) ----------------
__global__ __launch_bounds__(256) void gcn_init(float* __restrict__ out,
                                                const float* __restrict__ bias) {
    int idx = blockIdx.x * 256 + threadIdx.x;
    if (idx < N_NODES * D) out[idx] = bias[idx & 63];
}
__global__ __launch_bounds__(256) void gcn_scatter(const float* __restrict__ support,
                                                   const float* __restrict__ adj,
                                                   const int* __restrict__ src,
                                                   const int* __restrict__ dst,
                                                   float* __restrict__ out) {
    int tid = threadIdx.x;
    int e = blockIdx.x * 4 + (tid >> 6);
    if (e >= N_EDGES) return;
    int lane = tid & 63;
    float v = adj[e] * support[(long)src[e] * D + lane];
    atomicAdd(&out[(long)dst[e] * D + lane], v);
}

extern "C" void kernel_launch(void* const* d_in, const int* in_sizes, int n_in,
                              void* d_out, int out_size, void* d_ws, size_t ws_size,
                              hipStream_t stream) {
    const float* x      = (const float*)d_in[0];
    const float* weight = (const float*)d_in[1];
    const float* bias   = (const float*)d_in[2];
    const float* adj    = (const float*)d_in[3];
    const int*   src    = (const int*)d_in[4];
    const int*   dst    = (const int*)d_in[5];
    float* out = (float*)d_out;

    // workspace layout
    float* support = (float*)d_ws;                       // 25,600,000 B
    int2*  edges   = (int2*)(support + N_NODES * D);     // 12,800,000 B
    int*   counts  = (int*)(edges + N_EDGES);            // 400,000 B
    int*   offs    = counts + N_NODES;                   // 400,000 B
    int*   cursor  = offs + N_NODES;                     // 400,000 B
    int*   bsums   = cursor + N_NODES;                   // 512 B
    size_t needed = (char*)(bsums + 128) - (char*)d_ws;

    hipLaunchKernelGGL(gcn_gemm, dim3((N_NODES + GR - 1) / GR), dim3(256), 0, stream,
                       x, weight, support);

    if (ws_size >= needed) {
        hipMemsetAsync(counts, 0, N_NODES * sizeof(int), stream);
        hipLaunchKernelGGL(gcn_count, dim3(N_EDGES / 256), dim3(256), 0, stream, dst, counts);
        hipLaunchKernelGGL(gcn_scan1, dim3(NB1), dim3(256), 0, stream, counts, offs, bsums);
        hipLaunchKernelGGL(gcn_scan2, dim3(1), dim3(128), 0, stream, bsums);
        hipLaunchKernelGGL(gcn_scan3, dim3((N_NODES + 255) / 256), dim3(256), 0, stream,
                           offs, bsums, cursor);
        hipLaunchKernelGGL(gcn_fill, dim3(N_EDGES / 256), dim3(256), 0, stream,
                           src, dst, adj, cursor, edges);
        hipLaunchKernelGGL(gcn_gather, dim3((N_NODES + 3) / 4), dim3(256), 0, stream,
                           support, edges, offs, counts, bias, out);
    } else {
        // fallback: atomic scatter path
        hipLaunchKernelGGL(gcn_init, dim3((N_NODES * D) / 256), dim3(256), 0, stream, out, bias);
        hipLaunchKernelGGL(gcn_scatter, dim3(N_EDGES / 4), dim3(256), 0, stream,
                           support, adj, src, dst, out);
    }
}

// Round 3
// 368.112 us; speedup vs baseline: 1.3411x; 1.3081x over previous
//
#include <hip/hip_runtime.h>

#define N_NODES 100000
#define N_EDGES 1600000
#define D 64

// ---------------- GEMM: support = X @ W ----------------
// W (16 KB) staged in LDS as float4[k][c4]. Each thread: 2 rows, one float4
// column group. Low VGPR, high occupancy; x reads are 16-lane broadcasts.
__global__ __launch_bounds__(256) void gcn_gemm(const float* __restrict__ x,
                                                const float* __restrict__ w,
                                                float* __restrict__ support) {
    __shared__ float4 wsh[64 * 16];
    int tid = threadIdx.x;
    const float4* w4 = (const float4*)w;
    for (int i = tid; i < 64 * 16; i += 256) wsh[i] = w4[i];
    __syncthreads();

    int idx = blockIdx.x * 256 + tid;      // 800000 threads total
    int rowpair = idx >> 4;                // 0..49999
    int c4 = idx & 15;
    long r0 = (long)rowpair * 2;
    const float4* xr0 = (const float4*)(x + r0 * D);
    const float4* xr1 = (const float4*)(x + (r0 + 1) * D);

    float4 a0 = make_float4(0.f, 0.f, 0.f, 0.f);
    float4 a1 = make_float4(0.f, 0.f, 0.f, 0.f);
    #pragma unroll 4
    for (int k4 = 0; k4 < 16; ++k4) {
        float4 xv0 = xr0[k4];
        float4 xv1 = xr1[k4];
        float4 w0 = wsh[(4 * k4 + 0) * 16 + c4];
        float4 w1 = wsh[(4 * k4 + 1) * 16 + c4];
        float4 w2 = wsh[(4 * k4 + 2) * 16 + c4];
        float4 w3 = wsh[(4 * k4 + 3) * 16 + c4];
        a0 += w0 * xv0.x + w1 * xv0.y + w2 * xv0.z + w3 * xv0.w;
        a1 += w0 * xv1.x + w1 * xv1.y + w2 * xv1.z + w3 * xv1.w;
    }
    float4* s4 = (float4*)support;
    s4[r0 * 16 + c4] = a0;
    s4[(r0 + 1) * 16 + c4] = a1;
}

// ---------------- binning: counting sort by dst ----------------
__global__ __launch_bounds__(256) void gcn_count(const int* __restrict__ dst,
                                                 int* __restrict__ counts) {
    int e = blockIdx.x * 256 + threadIdx.x;
    if (e < N_EDGES) atomicAdd(&counts[dst[e]], 1);
}

#define SCAN_B 1024
__global__ __launch_bounds__(256) void gcn_scan1(const int* __restrict__ counts,
                                                 int* __restrict__ offs,
                                                 int* __restrict__ bsums) {
    __shared__ int sh[256];
    int tid = threadIdx.x;
    int base = blockIdx.x * SCAN_B + tid * 4;
    int v0 = (base + 0 < N_NODES) ? counts[base + 0] : 0;
    int v1 = (base + 1 < N_NODES) ? counts[base + 1] : 0;
    int v2 = (base + 2 < N_NODES) ? counts[base + 2] : 0;
    int v3 = (base + 3 < N_NODES) ? counts[base + 3] : 0;
    int local = v0 + v1 + v2 + v3;
    sh[tid] = local;
    __syncthreads();
    for (int off = 1; off < 256; off <<= 1) {
        int t = 0;
        if (tid >= off) t = sh[tid - off];
        __syncthreads();
        if (tid >= off) sh[tid] += t;
        __syncthreads();
    }
    int excl = sh[tid] - local;
    if (base + 0 < N_NODES) offs[base + 0] = excl;
    if (base + 1 < N_NODES) offs[base + 1] = excl + v0;
    if (base + 2 < N_NODES) offs[base + 2] = excl + v0 + v1;
    if (base + 3 < N_NODES) offs[base + 3] = excl + v0 + v1 + v2;
    if (tid == 255) bsums[blockIdx.x] = sh[255];
}

#define NB1 98  // ceil(100000/1024)
__global__ __launch_bounds__(128) void gcn_scan2(int* __restrict__ bsums) {
    __shared__ int sh[128];
    int tid = threadIdx.x;
    int orig = (tid < NB1) ? bsums[tid] : 0;
    sh[tid] = orig;
    __syncthreads();
    for (int off = 1; off < 128; off <<= 1) {
        int t = 0;
        if (tid >= off) t = sh[tid - off];
        __syncthreads();
        if (tid >= off) sh[tid] += t;
        __syncthreads();
    }
    if (tid < NB1) bsums[tid] = sh[tid] - orig;  // exclusive
}

__global__ __launch_bounds__(256) void gcn_scan3(int* __restrict__ offs,
                                                 const int* __restrict__ bsums,
                                                 int* __restrict__ cursor) {
    int i = blockIdx.x * 256 + threadIdx.x;
    if (i < N_NODES) {
        int o = offs[i] + bsums[i >> 10];
        offs[i] = o;
        cursor[i] = o;
    }
}

__global__ __launch_bounds__(256) void gcn_fill(const int* __restrict__ src,
                                                const int* __restrict__ dst,
                                                const float* __restrict__ adj,
                                                int* __restrict__ cursor,
                                                long long* __restrict__ edges) {
    int e = blockIdx.x * 256 + threadIdx.x;
    if (e < N_EDGES) {
        int d = dst[e];
        int pos = atomicAdd(&cursor[d], 1);
        // pack (src, adj) little-endian: src at +0, adj at +4
        long long packed = ((long long)(unsigned)__float_as_int(adj[e]) << 32)
                         | (unsigned)src[e];
        __builtin_nontemporal_store(packed, &edges[pos]);
    }
}

// ---------------- gather: one wave per node, LDS edge staging, ILP-8 ----------------
__global__ __launch_bounds__(256) void gcn_gather(const float* __restrict__ support,
                                                  const int2* __restrict__ edges,
                                                  const int* __restrict__ offs,
                                                  const int* __restrict__ counts,
                                                  const float* __restrict__ bias,
                                                  float* __restrict__ out) {
    __shared__ int2 eL[4][64];
    int tid = threadIdx.x;
    int wv = tid >> 6, lane = tid & 63;
    int n = blockIdx.x * 4 + wv;            // grid = 25000, always < N_NODES
    int start = offs[n];
    int cnt = counts[n];
    float acc = bias[lane];

    for (int c = 0; c < cnt; c += 64) {
        int rem = min(64, cnt - c);
        if (lane < rem) eL[wv][lane] = edges[start + c + lane];
        __builtin_amdgcn_wave_barrier();    // same-wave DS ordering; no block barrier needed
        int j = 0;
        for (; j + 8 <= rem; j += 8) {
            int2 e0 = eL[wv][j + 0], e1 = eL[wv][j + 1];
            int2 e2 = eL[wv][j + 2], e3 = eL[wv][j + 3];
            int2 e4 = eL[wv][j + 4], e5 = eL[wv][j + 5];
            int2 e6 = eL[wv][j + 6], e7 = eL[wv][j + 7];
            float v0 = support[(long)e0.x * D + lane];
            float v1 = support[(long)e1.x * D + lane];
            float v2 = support[(long)e2.x * D + lane];
            float v3 = support[(long)e3.x * D + lane];
            float v4 = support[(long)e4.x * D + lane];
            float v5 = support[(long)e5.x * D + lane];
            float v6 = support[(long)e6.x * D + lane];
            float v7 = support[(long)e7.x * D + lane];
            acc += __int_as_float(e0.y) * v0;
            acc += __int_as_float(e1.y) * v1;
            acc += __int_as_float(e2.y) * v2;
            acc += __int_as_float(e3.y) * v3;
            acc += __int_as_float(e4.y) * v4;
            acc += __int_as_float(e5.y) * v5;
            acc += __int_as_float(e6.y) * v6;
            acc += __int_as_float(e7.y) * v7;
        }
        for (; j < rem; ++j) {
            int2 e0 = eL[wv][j];
            acc += __int_as_float(e0.y) * support[(long)e0.x * D + lane];
        }
        __builtin_amdgcn_wave_barrier();
    }
    __builtin_nontemporal_store(acc, &out[(long)n * D + lane]);
}

extern "C" void kernel_launch(void* const* d_in, const int* in_sizes, int n_in,
                              void* d_out, int out_size, void* d_ws, size_t ws_size,
                              hipStream_t stream) {
    const float* x      = (const float*)d_in[0];
    const float* weight = (const float*)d_in[1];
    const float* bias   = (const float*)d_in[2];
    const float* adj    = (const float*)d_in[3];
    const int*   src    = (const int*)d_in[4];
    const int*   dst    = (const int*)d_in[5];
    float* out = (float*)d_out;

    // workspace layout (~39.6 MB)
    float* support   = (float*)d_ws;                     // 25,600,000 B
    long long* edges = (long long*)(support + N_NODES * D); // 12,800,000 B
    int*   counts    = (int*)(edges + N_EDGES);          // 400,000 B
    int*   offs      = counts + N_NODES;                 // 400,000 B
    int*   cursor    = offs + N_NODES;                   // 400,000 B
    int*   bsums     = cursor + N_NODES;                 // 512 B

    hipLaunchKernelGGL(gcn_gemm, dim3(N_NODES * 16 / 2 / 256), dim3(256), 0, stream,
                       x, weight, support);
    hipMemsetAsync(counts, 0, N_NODES * sizeof(int), stream);
    hipLaunchKernelGGL(gcn_count, dim3(N_EDGES / 256), dim3(256), 0, stream, dst, counts);
    hipLaunchKernelGGL(gcn_scan1, dim3(NB1), dim3(256), 0, stream, counts, offs, bsums);
    hipLaunchKernelGGL(gcn_scan2, dim3(1), dim3(128), 0, stream, bsums);
    hipLaunchKernelGGL(gcn_scan3, dim3((N_NODES + 255) / 256), dim3(256), 0, stream,
                       offs, bsums, cursor);
    hipLaunchKernelGGL(gcn_fill, dim3(N_EDGES / 256), dim3(256), 0, stream,
                       src, dst, adj, cursor, edges);
    hipLaunchKernelGGL(gcn_gather, dim3(N_NODES / 4), dim3(256), 0, stream,
                       support, (const int2*)edges, offs, counts, bias, out);
}

// Round 4
// 315.711 us; speedup vs baseline: 1.5637x; 1.1660x over previous
//
#include <hip/hip_runtime.h>

#define N_NODES 100000
#define N_EDGES 1600000
#define D 64

#define NSEG 8                         // dst-space segments, pinned to XCDs via blockIdx%8
#define SEG_NODES (N_NODES / NSEG)     // 12500
#define FILL_WPS 128                   // workgroups per segment
#define FILL_CH ((N_EDGES + FILL_WPS - 1) / FILL_WPS)  // 12500 edges per chunk

// ---------------- GEMM: support = X @ W ----------------
__global__ __launch_bounds__(256) void gcn_gemm(const float* __restrict__ x,
                                                const float* __restrict__ w,
                                                float* __restrict__ support) {
    __shared__ float4 wsh[64 * 16];
    int tid = threadIdx.x;
    const float4* w4 = (const float4*)w;
    for (int i = tid; i < 64 * 16; i += 256) wsh[i] = w4[i];
    __syncthreads();

    int idx = blockIdx.x * 256 + tid;
    int rowpair = idx >> 4;
    int c4 = idx & 15;
    long r0 = (long)rowpair * 2;
    const float4* xr0 = (const float4*)(x + r0 * D);
    const float4* xr1 = (const float4*)(x + (r0 + 1) * D);

    float4 a0 = make_float4(0.f, 0.f, 0.f, 0.f);
    float4 a1 = make_float4(0.f, 0.f, 0.f, 0.f);
    #pragma unroll 4
    for (int k4 = 0; k4 < 16; ++k4) {
        float4 xv0 = xr0[k4];
        float4 xv1 = xr1[k4];
        float4 w0 = wsh[(4 * k4 + 0) * 16 + c4];
        float4 w1 = wsh[(4 * k4 + 1) * 16 + c4];
        float4 w2 = wsh[(4 * k4 + 2) * 16 + c4];
        float4 w3 = wsh[(4 * k4 + 3) * 16 + c4];
        a0 += w0 * xv0.x + w1 * xv0.y + w2 * xv0.z + w3 * xv0.w;
        a1 += w0 * xv1.x + w1 * xv1.y + w2 * xv1.z + w3 * xv1.w;
    }
    float4* s4 = (float4*)support;
    s4[r0 * 16 + c4] = a0;
    s4[(r0 + 1) * 16 + c4] = a1;
}

// ---------------- binning: XCD-segmented counting sort by dst ----------------
__global__ __launch_bounds__(256) void gcn_count_seg(const int* __restrict__ dst,
                                                     int* __restrict__ counts) {
    int seg = blockIdx.x & (NSEG - 1);
    int w = blockIdx.x >> 3;
    int lo = seg * SEG_NODES, hi = lo + SEG_NODES;
    int e0 = w * FILL_CH;
    int e1 = min(e0 + FILL_CH, N_EDGES);
    for (int e = e0 + (int)threadIdx.x; e < e1; e += 256) {
        int d = dst[e];
        if (d >= lo && d < hi) atomicAdd(&counts[d], 1);
    }
}

#define SCAN_B 1024
__global__ __launch_bounds__(256) void gcn_scan1(const int* __restrict__ counts,
                                                 int* __restrict__ offs,
                                                 int* __restrict__ bsums) {
    __shared__ int sh[256];
    int tid = threadIdx.x;
    int base = blockIdx.x * SCAN_B + tid * 4;
    int v0 = (base + 0 < N_NODES) ? counts[base + 0] : 0;
    int v1 = (base + 1 < N_NODES) ? counts[base + 1] : 0;
    int v2 = (base + 2 < N_NODES) ? counts[base + 2] : 0;
    int v3 = (base + 3 < N_NODES) ? counts[base + 3] : 0;
    int local = v0 + v1 + v2 + v3;
    sh[tid] = local;
    __syncthreads();
    for (int off = 1; off < 256; off <<= 1) {
        int t = 0;
        if (tid >= off) t = sh[tid - off];
        __syncthreads();
        if (tid >= off) sh[tid] += t;
        __syncthreads();
    }
    int excl = sh[tid] - local;
    if (base + 0 < N_NODES) offs[base + 0] = excl;
    if (base + 1 < N_NODES) offs[base + 1] = excl + v0;
    if (base + 2 < N_NODES) offs[base + 2] = excl + v0 + v1;
    if (base + 3 < N_NODES) offs[base + 3] = excl + v0 + v1 + v2;
    if (tid == 255) bsums[blockIdx.x] = sh[255];
}

#define NB1 98  // ceil(100000/1024)
__global__ __launch_bounds__(128) void gcn_scan2(int* __restrict__ bsums) {
    __shared__ int sh[128];
    int tid = threadIdx.x;
    int orig = (tid < NB1) ? bsums[tid] : 0;
    sh[tid] = orig;
    __syncthreads();
    for (int off = 1; off < 128; off <<= 1) {
        int t = 0;
        if (tid >= off) t = sh[tid - off];
        __syncthreads();
        if (tid >= off) sh[tid] += t;
        __syncthreads();
    }
    if (tid < NB1) bsums[tid] = sh[tid] - orig;  // exclusive
}

__global__ __launch_bounds__(256) void gcn_scan3(int* __restrict__ offs,
                                                 const int* __restrict__ bsums,
                                                 int* __restrict__ cursor) {
    int i = blockIdx.x * 256 + threadIdx.x;
    if (i < N_NODES) {
        int o = offs[i] + bsums[i >> 10];
        offs[i] = o;
        cursor[i] = o;
    }
}

// fill: segment s (= blockIdx%8, pinned to XCD s by round-robin dispatch) only
// scatters edges with dst in its 12500-node range. Active write window =
// 12500 cursor-front lines (~800 KB) stays in that XCD's L2 -> lines fill
// fully before write-back. Normal stores (L2-cacheable), NOT nontemporal.
__global__ __launch_bounds__(256) void gcn_fill_seg(const int* __restrict__ src,
                                                    const int* __restrict__ dst,
                                                    const float* __restrict__ adj,
                                                    int* __restrict__ cursor,
                                                    int2* __restrict__ edges) {
    int seg = blockIdx.x & (NSEG - 1);
    int w = blockIdx.x >> 3;
    int lo = seg * SEG_NODES, hi = lo + SEG_NODES;
    int e0 = w * FILL_CH;
    int e1 = min(e0 + FILL_CH, N_EDGES);
    for (int e = e0 + (int)threadIdx.x; e < e1; e += 256) {
        int d = dst[e];
        if (d >= lo && d < hi) {
            int pos = atomicAdd(&cursor[d], 1);
            edges[pos] = make_int2(src[e], __float_as_int(adj[e]));
        }
    }
}

// ---------------- gather: one wave per node, LDS edge staging, ILP-8 ----------------
__global__ __launch_bounds__(256) void gcn_gather(const float* __restrict__ support,
                                                  const int2* __restrict__ edges,
                                                  const int* __restrict__ offs,
                                                  const int* __restrict__ counts,
                                                  const float* __restrict__ bias,
                                                  float* __restrict__ out) {
    __shared__ int2 eL[4][64];
    int tid = threadIdx.x;
    int wv = tid >> 6, lane = tid & 63;
    int n = blockIdx.x * 4 + wv;
    int start = offs[n];
    int cnt = counts[n];
    float acc = bias[lane];

    for (int c = 0; c < cnt; c += 64) {
        int rem = min(64, cnt - c);
        if (lane < rem) eL[wv][lane] = edges[start + c + lane];
        __builtin_amdgcn_wave_barrier();
        int j = 0;
        for (; j + 8 <= rem; j += 8) {
            int2 e0 = eL[wv][j + 0], e1 = eL[wv][j + 1];
            int2 e2 = eL[wv][j + 2], e3 = eL[wv][j + 3];
            int2 e4 = eL[wv][j + 4], e5 = eL[wv][j + 5];
            int2 e6 = eL[wv][j + 6], e7 = eL[wv][j + 7];
            float v0 = support[(long)e0.x * D + lane];
            float v1 = support[(long)e1.x * D + lane];
            float v2 = support[(long)e2.x * D + lane];
            float v3 = support[(long)e3.x * D + lane];
            float v4 = support[(long)e4.x * D + lane];
            float v5 = support[(long)e5.x * D + lane];
            float v6 = support[(long)e6.x * D + lane];
            float v7 = support[(long)e7.x * D + lane];
            acc += __int_as_float(e0.y) * v0;
            acc += __int_as_float(e1.y) * v1;
            acc += __int_as_float(e2.y) * v2;
            acc += __int_as_float(e3.y) * v3;
            acc += __int_as_float(e4.y) * v4;
            acc += __int_as_float(e5.y) * v5;
            acc += __int_as_float(e6.y) * v6;
            acc += __int_as_float(e7.y) * v7;
        }
        for (; j < rem; ++j) {
            int2 e0 = eL[wv][j];
            acc += __int_as_float(e0.y) * support[(long)e0.x * D + lane];
        }
        __builtin_amdgcn_wave_barrier();
    }
    __builtin_nontemporal_store(acc, &out[(long)n * D + lane]);
}

extern "C" void kernel_launch(void* const* d_in, const int* in_sizes, int n_in,
                              void* d_out, int out_size, void* d_ws, size_t ws_size,
                              hipStream_t stream) {
    const float* x      = (const float*)d_in[0];
    const float* weight = (const float*)d_in[1];
    const float* bias   = (const float*)d_in[2];
    const float* adj    = (const float*)d_in[3];
    const int*   src    = (const int*)d_in[4];
    const int*   dst    = (const int*)d_in[5];
    float* out = (float*)d_out;

    float* support = (float*)d_ws;                        // 25,600,000 B
    int2*  edges   = (int2*)(support + N_NODES * D);      // 12,800,000 B
    int*   counts  = (int*)(edges + N_EDGES);             // 400,000 B
    int*   offs    = counts + N_NODES;                    // 400,000 B
    int*   cursor  = offs + N_NODES;                      // 400,000 B
    int*   bsums   = cursor + N_NODES;                    // 512 B

    hipLaunchKernelGGL(gcn_gemm, dim3(N_NODES * 16 / 2 / 256), dim3(256), 0, stream,
                       x, weight, support);
    hipMemsetAsync(counts, 0, N_NODES * sizeof(int), stream);
    hipLaunchKernelGGL(gcn_count_seg, dim3(NSEG * FILL_WPS), dim3(256), 0, stream,
                       dst, counts);
    hipLaunchKernelGGL(gcn_scan1, dim3(NB1), dim3(256), 0, stream, counts, offs, bsums);
    hipLaunchKernelGGL(gcn_scan2, dim3(1), dim3(128), 0, stream, bsums);
    hipLaunchKernelGGL(gcn_scan3, dim3((N_NODES + 255) / 256), dim3(256), 0, stream,
                       offs, bsums, cursor);
    hipLaunchKernelGGL(gcn_fill_seg, dim3(NSEG * FILL_WPS), dim3(256), 0, stream,
                       src, dst, adj, cursor, edges);
    hipLaunchKernelGGL(gcn_gather, dim3(N_NODES / 4), dim3(256), 0, stream,
                       support, edges, offs, counts, bias, out);
}